// Round 1
// 966.101 us; speedup vs baseline: 1.0884x; 1.0884x over previous
//
#include <hip/hip_runtime.h>
#include <hip/hip_bf16.h>
#include <hip/hip_fp16.h>

#define T_DIM 8192
#define H_DIM 3200
#define I_DIM 12800

typedef int v4i __attribute__((ext_vector_type(4)));
typedef _Float16 h8 __attribute__((ext_vector_type(8)));

__device__ __forceinline__ void gload16(const void* g, void* l) {
    __builtin_amdgcn_global_load_lds(
        (const __attribute__((address_space(1))) unsigned int*)g,
        (__attribute__((address_space(3))) unsigned int*)l, 16, 0, 0);
}

// ---------------- int32 -> int8 repack (memory-bound) ----------------
__global__ __launch_bounds__(256) void repack_kernel(const int* __restrict__ src,
                                                     unsigned int* __restrict__ dst,
                                                     long n4) {
    long i = (long)blockIdx.x * blockDim.x + threadIdx.x;
    long stride = (long)gridDim.x * blockDim.x;
    for (; i < n4; i += stride) {
        int4 v = ((const int4*)src)[i];
        dst[i] = (unsigned int)((v.x & 255) | ((v.y & 255) << 8) |
                                ((v.z & 255) << 16) | ((v.w & 255) << 24));
    }
}

// ---------------- i8 GEMM, C[M][N] = A[M][K] * B[N][K]^T ----------------
// 256x256 tile, 8-phase counted-vmcnt schedule (T2+T3+T4+T5, m201 template
// ported to i8). 512 threads = 8 waves (2M x 4N), per-wave output 128x64,
// mfma_i32_16x16x64_i8. K is consumed in 64-byte K-halves; LDS = ring of 4
// half-K-tile units per operand (4 x 16 KiB x 2 = 128 KiB). Staging via
// global_load_lds width-16 with LINEAR LDS dest + pre-swizzled GLOBAL source
// (rule 21); ds_read applies the same XOR swizzle: 16B-chunk cc ^= (row>>1)&3
// -> each 16-lane read group covers all 32 banks (2 lanes/bank = free).
// vmcnt(6) gate once per K-tile (3 units in flight), never drained to 0.
// strideA/strideB in BYTES. EPI=0: fp16 out. EPI=1: fp32 of fp16-rounded.
// Epilogue guards col < Ntrue (fc2's N=3200 runs on a 13-tile grid whose last
// tile over-reads B into adjacent workspace -- valid memory, stores guarded).
template <int EPI>
__global__ __launch_bounds__(512, 2) void gemm_i8_8ph(
    const signed char* __restrict__ A, long strideA,
    const signed char* __restrict__ B, long strideB,
    int Ntrue, int K, int ldc,
    const float* __restrict__ rowscale, const float* __restrict__ colscale,
    const float* __restrict__ bias, void* __restrict__ Cout) {
    __shared__ signed char lds[131072];
    signed char* ldsA = lds;           // 4 units x 16384 B (256 rows x 64 B)
    signed char* ldsB = lds + 65536;   // 4 units x 16384 B

    const int tid = threadIdx.x;
    const int lane = tid & 63, wid = tid >> 6;
    const int wr = wid >> 2, wc = wid & 3;
    const int bm = blockIdx.x, bn = blockIdx.y;
    const long Arow0 = (long)bm * 256;
    const long Bcol0 = (long)bn * 256;

    // Staging: unit = 256 rows x 64 B = 1024 chunks of 16 B; thread handles
    // chunks c0 = tid and c1 = tid+512. LDS dest is linear (uniform base +
    // lane*16); the swizzle is folded into the per-lane GLOBAL source chunk.
    const int c0 = tid, c1 = tid + 512;
    const int r0 = c0 >> 2, r1 = c1 >> 2;
    const int s0 = (((c0 & 3) ^ ((r0 >> 1) & 3)) << 4);
    const int s1 = (((c1 & 3) ^ ((r1 >> 1) & 3)) << 4);
    const signed char* Ag0 = A + (Arow0 + r0) * strideA + s0;
    const signed char* Ag1 = A + (Arow0 + r1) * strideA + s1;
    const signed char* Bg0 = B + (Bcol0 + r0) * strideB + s0;
    const signed char* Bg1 = B + (Bcol0 + r1) * strideB + s1;
    const int d0 = c0 * 16, d1 = c1 * 16;

    const int NH = K >> 6;   // number of 64-byte K-halves
    const int nkt = K >> 7;  // loop bodies (1 K-tile = 2 halves = 4 phases)

    // Stage unit for K-half h. Slot = h&3 (unclamped: tail stages land in
    // dead slots); source k-offset clamped to stay in-bounds (data unused).
#define STAGE_A(h)                                  \
    {                                               \
        const int hc_ = (h) < NH ? (h) : NH - 1;    \
        const long ko_ = (long)hc_ << 6;            \
        signed char* d_ = ldsA + (((h) & 3) << 14); \
        gload16(Ag0 + ko_, d_ + d0);                \
        gload16(Ag1 + ko_, d_ + d1);                \
    }
#define STAGE_B(h)                                  \
    {                                               \
        const int hc_ = (h) < NH ? (h) : NH - 1;    \
        const long ko_ = (long)hc_ << 6;            \
        signed char* d_ = ldsB + (((h) & 3) << 14); \
        gload16(Bg0 + ko_, d_ + d0);                \
        gload16(Bg1 + ko_, d_ + d1);                \
    }

    // Fragment read offsets. Lane reads 16 B at (row, k-chunk q) -> LDS chunk
    // q ^ ((row>>1)&3). Since row = base16 + r, the XOR reduces to a per-lane
    // constant: swz = q ^ ((r>>1)&3). Frag i lives at +i*1024.
    const int r = lane & 15, q = lane >> 4;
    const int swz = ((q ^ ((r >> 1) & 3)) << 4);
    const int aoff = (wr * 128 + r) * 64 + swz;  // + i*1024, i = 0..7
    const int boff = (wc * 64 + r) * 64 + swz;   // + n*1024, n = 0..3

    v4i acc[8][4] = {};
    v4i af[4], bf[4];

    // Phase: read frags -> issue 1 stage -> barrier -> lgkmcnt(0) ->
    // setprio(1) -> 16 MFMA -> setprio(0) -> [gate] -> barrier.
#define PHASE(SLOTA, SLOTB, AIDX, LOADB, ACCOFF, STAGE_STMT, GATE_STMT)     \
    {                                                                       \
        _Pragma("unroll") for (int i = 0; i < 4; ++i)                       \
            af[i] = *(const v4i*)((SLOTA) + aoff + ((AIDX) + i) * 1024);    \
        if (LOADB) {                                                        \
            _Pragma("unroll") for (int n = 0; n < 4; ++n)                   \
                bf[n] = *(const v4i*)((SLOTB) + boff + n * 1024);           \
        }                                                                   \
        STAGE_STMT;                                                         \
        __builtin_amdgcn_s_barrier();                                       \
        asm volatile("s_waitcnt lgkmcnt(0)");                               \
        __builtin_amdgcn_s_setprio(1);                                      \
        _Pragma("unroll") for (int m = 0; m < 4; ++m)                       \
            _Pragma("unroll") for (int n = 0; n < 4; ++n)                   \
                acc[m + (ACCOFF)][n] = __builtin_amdgcn_mfma_i32_16x16x64_i8( \
                    af[m], bf[n], acc[m + (ACCOFF)][n], 0, 0, 0);           \
        __builtin_amdgcn_s_setprio(0);                                      \
        GATE_STMT;                                                          \
        __builtin_amdgcn_s_barrier();                                       \
    }

    // Prologue: stage stream prefix B0,A0,B1,A1,B2,A2,B3; gate leaves the
    // newest 3 units (6 loads) in flight -- halves 0,1 guaranteed resident.
    STAGE_B(0); STAGE_A(0); STAGE_B(1); STAGE_A(1);
    STAGE_B(2); STAGE_A(2); STAGE_B(3);
    asm volatile("s_waitcnt vmcnt(6)");
    __builtin_amdgcn_s_barrier();

    for (int kt = 0; kt < nkt; ++kt) {
        const int g = kt << 1;
        const signed char* sA0 = ldsA + ((g & 3) << 14);
        const signed char* sB0 = ldsB + ((g & 3) << 14);
        const signed char* sA1 = ldsA + (((g + 1) & 3) << 14);
        const signed char* sB1 = ldsB + (((g + 1) & 3) << 14);
        // ph0: half g,   A0-3 x B0-3 ; stage A(g+3) (slot of A(g-1), dead)
        PHASE(sA0, sB0, 0, true, 0, STAGE_A(g + 3), );
        // ph1: half g,   A4-7 x B0-3 ; stage B(g+4) (slot of B(g), read ph0)
        PHASE(sA0, sB0, 4, false, 4, STAGE_B(g + 4), );
        // ph2: half g+1, A0-3 x B0-3 ; stage A(g+4) (slot of A(g), read ph0-1)
        PHASE(sA1, sB1, 0, true, 0, STAGE_A(g + 4), );
        // ph3: half g+1, A4-7 x B0-3 ; stage B(g+5); counted gate vmcnt(6)
        PHASE(sA1, sB1, 4, false, 4, STAGE_B(g + 5),
              asm volatile("s_waitcnt vmcnt(6)"));
    }

    // Epilogue: C/D layout col = lane&15, row = (lane>>4)*4 + reg.
    const int row0 = bm * 256 + wr * 128;
    const int col0 = bn * 256 + wc * 64;
    const int r4 = (lane >> 4) << 2, cl = lane & 15;
#pragma unroll
    for (int m = 0; m < 8; ++m) {
        const int rowb = row0 + m * 16 + r4;
        float rs[4];
#pragma unroll
        for (int rr = 0; rr < 4; ++rr) rs[rr] = rowscale[rowb + rr];
#pragma unroll
        for (int n = 0; n < 4; ++n) {
            const int col = col0 + n * 16 + cl;
            if (col < Ntrue) {
                const float cs = colscale[col];
                const float bs = bias[col];
#pragma unroll
                for (int rr = 0; rr < 4; ++rr) {
                    float v = (float)acc[m][n][rr];
                    v = __fmul_rn(v, rs[rr]);
                    v = __fmul_rn(v, cs);
                    v = __fadd_rn(v, bs);
                    _Float16 hh = (_Float16)v;  // reference rounds to fp16
                    const size_t idx = (size_t)(rowb + rr) * ldc + col;
                    if (EPI == 0) ((_Float16*)Cout)[idx] = hh;
                    else ((float*)Cout)[idx] = (float)hh;
                }
            }
        }
    }
#undef PHASE
#undef STAGE_A
#undef STAGE_B
}

// -------- exact GELU + per-token dynamic int8 requant (in-place act_q) -------
__global__ __launch_bounds__(256) void gelu_quant(_Float16* __restrict__ fc1,
                                                  float* __restrict__ nscale) {
    __shared__ float gbuf[I_DIM];
    __shared__ float wmax[4];
    const int tid = threadIdx.x, lane = tid & 63, wid = tid >> 6;
    const long t = blockIdx.x;
    const h8* row = (const h8*)(fc1 + t * I_DIM);
    float lmax = 0.f;
    for (int c = tid; c < I_DIM / 8; c += 256) {
        h8 v = row[c];
#pragma unroll
        for (int j = 0; j < 8; ++j) {
            float x = (float)v[j];
            float e = erff(__fdiv_rn(x, 1.41421356237309504880f));
            float g = __fmul_rn(__fmul_rn(0.5f, x), __fadd_rn(1.0f, e));
            gbuf[c * 8 + j] = g;
            lmax = fmaxf(lmax, fabsf(g));
        }
    }
#pragma unroll
    for (int off = 32; off; off >>= 1) lmax = fmaxf(lmax, __shfl_xor(lmax, off, 64));
    if (lane == 0) wmax[wid] = lmax;
    __syncthreads();
    const float gmax = fmaxf(fmaxf(wmax[0], wmax[1]), fmaxf(wmax[2], wmax[3]));
    const float ns = gmax / 127.0f;
    if (tid == 0) nscale[t] = ns;
    unsigned long long* out = (unsigned long long*)(fc1 + t * I_DIM);  // in-place
    for (int c = tid; c < I_DIM / 8; c += 256) {
        unsigned long long pk = 0;
#pragma unroll
        for (int j = 0; j < 8; ++j) {
            float qv = rintf(__fdiv_rn(gbuf[c * 8 + j], ns));
            qv = fminf(fmaxf(qv, -127.f), 127.f);
            pk |= ((unsigned long long)(unsigned char)(signed char)(int)qv) << (8 * j);
        }
        out[c] = pk;
    }
}

extern "C" void kernel_launch(void* const* d_in, const int* in_sizes, int n_in,
                              void* d_out, int out_size, void* d_ws, size_t ws_size,
                              hipStream_t stream) {
    const int* hs = (const int*)d_in[0];        // [B,S,H] int8-in-int32
    const float* scale = (const float*)d_in[1]; // [T]
    const int* w1 = (const int*)d_in[2];        // [I,H]
    const float* w1s = (const float*)d_in[3];   // [I]
    const float* b1 = (const float*)d_in[4];    // [I]
    const int* w2 = (const int*)d_in[5];        // [H,I]
    const float* w2s = (const float*)d_in[6];   // [H]
    const float* b2 = (const float*)d_in[7];    // [H]

    char* ws = (char*)d_ws;
    signed char* xq = (signed char*)ws;                     // 26,214,400 B
    signed char* w1q = xq + (size_t)T_DIM * H_DIM;          // 40,960,000 B
    signed char* w2q = w1q + (size_t)I_DIM * H_DIM;         // 40,960,000 B
    _Float16* fc1h = (_Float16*)(w2q + (size_t)H_DIM * I_DIM);  // chunkT*I fp16
    const size_t fixed = (size_t)T_DIM * H_DIM + 2 * (size_t)I_DIM * H_DIM;

    // choose smallest chunk count whose workspace fits ws_size (deterministic)
    int nc = 1;
    while (nc < 16) {
        size_t need = fixed + ((size_t)T_DIM / nc) * I_DIM * 2 +
                      ((size_t)T_DIM / nc) * 4 + 256;
        if (need <= ws_size) break;
        nc <<= 1;
    }
    const int chunkT = T_DIM / nc;
    float* nscale = (float*)((char*)fc1h + (size_t)chunkT * I_DIM * 2);

    repack_kernel<<<2048, 256, 0, stream>>>(hs, (unsigned int*)xq, (long)T_DIM * H_DIM / 4);
    repack_kernel<<<2048, 256, 0, stream>>>(w1, (unsigned int*)w1q, (long)I_DIM * H_DIM / 4);
    repack_kernel<<<2048, 256, 0, stream>>>(w2, (unsigned int*)w2q, (long)H_DIM * I_DIM / 4);

    const int n2tiles = (H_DIM + 255) / 256;  // 13; last tile col-guarded
    for (int c = 0; c < nc; ++c) {
        const int t0 = c * chunkT;
        gemm_i8_8ph<0><<<dim3(chunkT / 256, I_DIM / 256), 512, 0, stream>>>(
            xq + (size_t)t0 * H_DIM, (long)H_DIM, w1q, (long)H_DIM,
            I_DIM, H_DIM, I_DIM,
            scale + t0, w1s, b1, (void*)fc1h);
        gelu_quant<<<chunkT, 256, 0, stream>>>(fc1h, nscale);
        gemm_i8_8ph<1><<<dim3(chunkT / 256, n2tiles), 512, 0, stream>>>(
            (const signed char*)fc1h, (long)I_DIM * 2, w2q, (long)I_DIM,
            H_DIM, I_DIM, H_DIM,
            nscale, w2s, b2,
            (void*)((float*)d_out + (size_t)t0 * H_DIM));
    }
}